// Round 9
// baseline (547.039 us; speedup 1.0000x reference)
//
#include <hip/hip_runtime.h>

// DILATE loss via the soft-DTW forward/backward identity:
//   E[i,j] = exp((V - R[i,j] - Rrev[i,j] + D[i,j]) / gamma)
// Round 9 pass: 2 waves/block (128 thr), 4 ADJACENT rows per lane
// (i0 = 256w + 4l) -> cross-lane shuffle only feeds cell r=0 (chain
// amortized 4x); 256 blocks = 1/CU; o via register window (b128/4 steps);
// boundary reads lane0-masked; packed-slab base maintained incrementally.
// Scaled domain R'' = R * (100/ln2) so softmin uses raw exp2/log2.

#define NSEQ 512
#define K2   144.269504088896f      // (1/gamma)*log2(e) = 100/ln2
#define SC   0.006931471805599453f  // ln2/100
#define BIGV 1e10f
#define ALPHA 0.5f
#define PACKN 262144                // N^2 floats per sample per direction

typedef float4 f4;
#define C4(v, c) ((c)==0 ? (v).x : (c)==1 ? (v).y : (c)==2 ? (v).z : (v).w)
// o-window element at position pos in [-4,3] relative to group base g0
#define OWIN(pos) ((pos) < 0 ? C4(wlo, (pos) + 4) : C4(whi, (pos)))

__device__ __forceinline__ int diag_off(int d) {
    if (d < 512) return (d * (d + 1)) >> 1;
    const int m = 1023 - d;
    return PACKN - ((m * (m + 1)) >> 1);
}

__global__ __launch_bounds__(128) void sdtw_pass(
    const float* __restrict__ outp, const float* __restrict__ targ,
    float* __restrict__ slabA, float* __restrict__ slabB,
    float* __restrict__ vals, float* __restrict__ vraw, int kbase)
{
    const int tid = threadIdx.x;
    const int w = tid >> 6, l = tid & 63;
    const int i0 = 256 * w + 4 * l;          // lane owns rows i0..i0+3
    const int dir = blockIdx.x & 1;
    const int kk  = blockIdx.x >> 1;
    const int k   = kbase + kk;
    const bool lane0 = (l == 0), lane63 = (l == 63);

    __shared__ __align__(16) float o_pad[1032];  // o[j] at [256+j], zeros outside
    __shared__ float t_sh[516];
    __shared__ float Rbf[772];                   // boundary row 255, col c at [c+1]

    for (int q = tid; q < 1032; q += 128) o_pad[q] = 0.f;
    for (int q = tid; q < 516;  q += 128) t_sh[q] = 0.f;
    for (int q = tid; q < 772;  q += 128) Rbf[q]  = BIGV;
    __syncthreads();
    for (int q = tid; q < NSEQ; q += 128) {      // dir 1: reversed sequences
        const int src = dir ? (NSEQ - 1 - q) : q;
        o_pad[256 + q] = outp[(size_t)k * NSEQ + src];
        t_sh[q]        = targ[(size_t)k * NSEQ + src];
    }
    __syncthreads();

    const float tr0 = t_sh[i0],     tr1 = t_sh[i0 + 1];
    const float tr2 = t_sh[i0 + 2], tr3 = t_sh[i0 + 3];

    float* __restrict__ sp = (dir ? slabB : slabA) + (size_t)kk * PACKN;

    float Pa[4], Pb[4];                           // rotating diag buffers
    #pragma unroll
    for (int r = 0; r < 4; ++r) { Pa[r] = BIGV; Pb[r] = BIGV; }
    float rfinal = BIGV;

    for (int ss = 0; ss < 17; ++ss) {
        const int mw = ss - 5 * w;                // wave-local window (lag 5)
        if (0 <= mw && mw < 12) {
            const int tb = (mw + 4 * w) * 64;     // global diag base
            int g0 = tb - i0;                     // group-base j0 of lane
            int d  = tb;                          // uniform diag index
            int basei = diag_off(d) - ((d > 511) ? (d - 511) : 0);
            f4 wlo = *(const f4*)&o_pad[256 + g0 - 4];
            f4 whi = *(const f4*)&o_pad[256 + g0];
            for (int ug = 0; ug < 16; ++ug) {
                const f4 wnx = *(const f4*)&o_pad[256 + g0 + 4];
                #pragma unroll
                for (int q = 0; q < 4; ++q) {     // u = 4*ug + q, diag d
                    float* P1 = (q & 1) ? Pb : Pa;   // diag d-1
                    float* P2 = (q & 1) ? Pa : Pb;   // diag d-2 -> dest d
                    const float sa = __shfl_up(P1[3], 1);  // R[i0-1, j0]   (d-1)
                    const float sb = __shfl_up(P2[3], 1);  // R[i0-1, j0-1] (d-2)
                    const int jq = g0 + q;               // j of cell r=0
                    float bdA = BIGV, bdB = BIGV;
                    if (w == 0) {
                        if (ss == 0 && ug == 0 && q == 0) bdB = 0.f;  // R[-1,-1]=0
                    } else if (lane0) {
                        const int ob = (jq > 0) ? jq : 0;
                        bdB = Rbf[ob];                   // R[255, j0-1]
                        bdA = Rbf[ob + 1];               // R[255, j0]
                    }
                    const float a0 = lane0 ? bdA : sa;
                    const float b0 = lane0 ? bdB : sb;
                    #pragma unroll
                    for (int rr = 0; rr < 4; ++rr) {
                        const int r = 3 - rr;            // descending preserves P2[r-1]
                        const float a = r ? P1[r - 1] : a0;   // R[i-1, j]
                        const float b = r ? P2[r - 1] : b0;   // R[i-1, j-1]
                        const float c = P1[r];                // R[i, j-1]
                        const float mn = fminf(fminf(a, b), c);
                        const float mx = fmaxf(fmaxf(a, b), c);
                        const float md = __builtin_amdgcn_fmed3f(a, b, c);
                        const float ssum = 1.f + __builtin_exp2f(mn - md)
                                               + __builtin_exp2f(mn - mx);
                        const float sm = mn - __builtin_log2f(ssum);
                        const float ov = OWIN(q - r);         // o[jq - r]
                        const float tv = (r == 0) ? tr0 : (r == 1) ? tr1
                                       : (r == 2) ? tr2 : tr3;
                        const float dv = tv - ov;
                        const float val = fmaf(dv * dv, K2, sm);
                        const bool act = ((unsigned)(jq - r) < 512u);
                        P2[r] = act ? val : BIGV;
                        if (act) sp[basei + i0 + r] = val;   // packed store
                        if (r == 3) {
                            if (w == 0 && lane63 && act) Rbf[jq - 2] = val; // col jq-3
                            if (w == 1 && mw == 11 && ug == 15 && q == 2)
                                rfinal = val;                // cell (511,511)
                        }
                    }
                    const int d1 = d + 1, d2 = 1022 - d;     // uniform SALU
                    basei += (d1 < d2) ? d1 : d2;
                    ++d;
                }
                wlo = whi; whi = wnx; g0 += 4;
            }
        }
        asm volatile("s_waitcnt lgkmcnt(0)\n\ts_barrier" ::: "memory");
    }
    if (w == 1 && lane63 && dir == 0) { vals[k] = rfinal * SC; vraw[k] = rfinal; }
}

// ---------------- pointwise E map-reduce ----------------
// E[i,j] = exp2(Vraw - A[i,j] - B[i',j'] + D[i,j]*K2); acc += E*(i-j)^2,
// with (i',j') = (511-i, 511-j) in the reverse pass's packed layout.
__global__ __launch_bounds__(256) void ereduce(
    const float* __restrict__ outp, const float* __restrict__ targ,
    const float* __restrict__ slabA, const float* __restrict__ slabB,
    const float* __restrict__ vraw, float* __restrict__ spart, int kbase)
{
    const int tid = threadIdx.x;
    const int sect = blockIdx.x & 7;
    const int kk = blockIdx.x >> 3;
    const int k = kbase + kk;

    __shared__ float t_sh[NSEQ], o_sh[NSEQ];
    __shared__ float red[4];
    for (int q = tid; q < NSEQ; q += 256) {
        t_sh[q] = targ[(size_t)k * NSEQ + q];
        o_sh[q] = outp[(size_t)k * NSEQ + q];
    }
    __syncthreads();

    const float* __restrict__ A  = slabA + (size_t)kk * PACKN;
    const float* __restrict__ Bs = slabB + (size_t)kk * PACKN;
    const float V = vraw[k];
    float acc = 0.f;
    const int dend = (sect == 7) ? 1023 : (sect * 128 + 128);
    for (int d = sect * 128; d < dend; ++d) {
        const int ilo = (d > 511) ? (d - 511) : 0;
        const int ihi = (d < 512) ? d : 511;
        const int dp  = 1022 - d;                       // reverse-pass diagonal
        const int iloB = (dp > 511) ? (dp - 511) : 0;
        const int baseA = diag_off(d) - ilo;
        const int baseB = diag_off(dp) + 511 - iloB;    // idxB = baseB - i
        for (int i = ilo + tid; i <= ihi; i += 256) {
            const float a = A[baseA + i];
            const float b = Bs[baseB - i];
            const float dv = t_sh[i] - o_sh[d - i];
            const float arg = fmaf(dv * dv, K2, V - a - b);
            const float E = __builtin_exp2f(arg);       // in [0, 1+eps]
            const float df = (float)(2 * i - d);        // i - j
            acc = fmaf(E * df, df, acc);
        }
    }
    for (int off = 32; off; off >>= 1) acc += __shfl_down(acc, off);
    if ((tid & 63) == 0) red[tid >> 6] = acc;
    __syncthreads();
    if (tid == 0) spart[k * 8 + sect] = red[0] + red[1] + red[2] + red[3];
}

__global__ void finalize_kernel(const float* __restrict__ vals,
                                const float* __restrict__ spart,
                                float* __restrict__ out, int B) {
    int t = threadIdx.x;    // 64 threads
    float v = 0.0f, s = 0.0f;
    for (int q = t; q < B; q += 64) v += vals[q];
    for (int q = t; q < 8 * B; q += 64) s += spart[q];
    for (int off = 32; off; off >>= 1) { v += __shfl_down(v, off); s += __shfl_down(s, off); }
    if (t == 0) {
        float loss_shape = v / (float)B;
        float loss_temporal = (s / (float)B) / ((float)NSEQ * (float)NSEQ);
        out[0] = ALPHA * loss_shape + (1.0f - ALPHA) * loss_temporal;
    }
}

extern "C" void kernel_launch(void* const* d_in, const int* in_sizes, int n_in,
                              void* d_out, int out_size, void* d_ws, size_t ws_size,
                              hipStream_t stream) {
    const float* outputs = (const float*)d_in[0];
    const float* targets = (const float*)d_in[1];
    const int B = in_sizes[0] / NSEQ;    // 64

    // ws: [0,256B) vals, [256,512B) vraw, [512,2560B) spart, [4096, ...) slabs
    float* vals  = (float*)d_ws;
    float* vraw  = vals + 64;
    float* spart = vals + 128;
    float* slabs = (float*)((char*)d_ws + 4096);

    const size_t per_sample = 2 * (size_t)PACKN * sizeof(float);   // 2 MiB (A+B)
    size_t avail = (ws_size > 4096) ? (ws_size - 4096) / per_sample : 0;
    int G = (int)((avail < (size_t)B) ? avail : (size_t)B);
    if (G < 1) G = 1;
    float* slabA = slabs;
    float* slabB = slabs + (size_t)G * PACKN;

    for (int kb = 0; kb < B; kb += G) {
        int g = (B - kb < G) ? (B - kb) : G;
        sdtw_pass<<<dim3(2 * g), dim3(128), 0, stream>>>(
            outputs, targets, slabA, slabB, vals, vraw, kb);
        ereduce<<<dim3(8 * g), dim3(256), 0, stream>>>(
            outputs, targets, slabA, slabB, vraw, spart, kb);
    }
    finalize_kernel<<<dim3(1), dim3(64), 0, stream>>>(vals, spart, (float*)d_out, B);
}